// Round 1
// baseline (602.194 us; speedup 1.0000x reference)
//
#include <hip/hip_runtime.h>
#include <math.h>

#define B_ROWS 131072
#define ROWS 128
#define XP 36   // Xs pitch (floats): 16B-aligned, bank-staggered
#define MP 36   // Ms pitch
#define LP 34   // Ls pitch (scalar access only)

// ---------------- precompute M = [Wr*Wp | 0.1*Wr ; Wn*Wp | 0.1*Wn], c = bias ----
__global__ void precompute_M(const float* __restrict__ Wp,
                             const float* __restrict__ Wr,
                             const float* __restrict__ Wn,
                             const float* __restrict__ bp,
                             const float* __restrict__ br,
                             const float* __restrict__ bn,
                             float* __restrict__ M,
                             float* __restrict__ c) {
  int o = blockIdx.x * 256 + threadIdx.x;          // 32*1024 outputs
  if (o < 32 * 1024) {
    int j = o >> 10, k = o & 1023;
    const float* W = (j < 16) ? Wr : Wn;
    int jj = j & 15;
    float v;
    if (k < 768) {
      double s = 0.0;
      for (int d = 0; d < 256; ++d)
        s += (double)W[jj * 256 + d] * (double)Wp[d * 768 + k];
      v = (float)s;
    } else {
      v = 0.1f * W[jj * 256 + (k - 768)];
    }
    M[o] = v;
  }
  if (blockIdx.x == 0 && threadIdx.x < 32) {
    int j = threadIdx.x, jj = j & 15;
    const float* W = (j < 16) ? Wr : Wn;
    const float* b = (j < 16) ? br : bn;
    double s = (double)b[jj];
    for (int d = 0; d < 256; ++d)
      s += (double)W[jj * 256 + d] * (double)bp[d];
    c[j] = (float)s;
  }
}

// ---------------- main fused kernel ------------------------------------------
__global__ __launch_bounds__(256, 3)
void router_main(const float* __restrict__ zn, const float* __restrict__ zs,
                 const float* __restrict__ zt, const float* __restrict__ nz,
                 const float* __restrict__ nr, const int* __restrict__ patches,
                 const float* __restrict__ M, const float* __restrict__ c,
                 float* __restrict__ out) {
  __shared__ float Xs[ROWS * XP];   // 18.0 KB
  __shared__ float Ms[32 * MP];     //  4.5 KB
  __shared__ float Ls[ROWS * LP];   // 17.4 KB
  const int t = threadIdx.x;
  const int row0 = blockIdx.x * ROWS;
  const int jg = t & 7;     // j = jg + 8*jj  (stride-8 -> conflict-free b128)
  const int rg = t >> 3;    // r = rg + 32*rr (in-wave rg 0..7 -> conflict-free)
  const int sr = t >> 3;    // staging row
  const int sk4 = t & 7;    // staging k-quad

  float accf[4][4];
  double accd[4][4];
#pragma unroll
  for (int a = 0; a < 4; ++a)
#pragma unroll
    for (int b = 0; b < 4; ++b) { accf[a][b] = 0.f; accd[a][b] = 0.0; }

  for (int s = 0; s < 32; ++s) {
    const int k0 = s * 32;
    const float* src; int col0;
    if (k0 < 256)      { src = zn; col0 = k0; }
    else if (k0 < 512) { src = zs; col0 = k0 - 256; }
    else if (k0 < 768) { src = zt; col0 = k0 - 512; }
    else               { src = nz; col0 = k0 - 768; }

    // global loads issued before the barrier: overlap previous compute
    float4 xg[4];
#pragma unroll
    for (int i = 0; i < 4; ++i)
      xg[i] = *(const float4*)&src[(size_t)(row0 + sr + 32 * i) * 256 + col0 + 4 * sk4];
    float4 mg = *(const float4*)&M[(size_t)(t >> 3) * 1024 + k0 + 4 * sk4];

    __syncthreads();   // previous iteration's LDS reads done
#pragma unroll
    for (int i = 0; i < 4; ++i)
      *(float4*)&Xs[(sr + 32 * i) * XP + 4 * sk4] = xg[i];
    *(float4*)&Ms[(t >> 3) * MP + 4 * sk4] = mg;
    __syncthreads();

#pragma unroll
    for (int ks = 0; ks < 8; ++ks) {
      const int k = 4 * ks;
      float4 m4[4], x4[4];
#pragma unroll
      for (int jj = 0; jj < 4; ++jj)
        m4[jj] = *(const float4*)&Ms[(jg + 8 * jj) * MP + k];
#pragma unroll
      for (int rr = 0; rr < 4; ++rr)
        x4[rr] = *(const float4*)&Xs[(rg + 32 * rr) * XP + k];
#pragma unroll
      for (int jj = 0; jj < 4; ++jj)
#pragma unroll
        for (int rr = 0; rr < 4; ++rr) {
          accf[jj][rr] += m4[jj].x * x4[rr].x;
          accf[jj][rr] += m4[jj].y * x4[rr].y;
          accf[jj][rr] += m4[jj].z * x4[rr].z;
          accf[jj][rr] += m4[jj].w * x4[rr].w;
        }
    }
    // fold 32-k chunk into f64 accumulator (keeps error ~3e-8 vs exact)
#pragma unroll
    for (int jj = 0; jj < 4; ++jj)
#pragma unroll
      for (int rr = 0; rr < 4; ++rr) { accd[jj][rr] += (double)accf[jj][rr]; accf[jj][rr] = 0.f; }
  }

  // gather the 32 pre-activation logits per row into LDS
#pragma unroll
  for (int jj = 0; jj < 4; ++jj) {
    const int j = jg + 8 * jj;
    const float cj = c[j];
#pragma unroll
    for (int rr = 0; rr < 4; ++rr) {
      const int r = rg + 32 * rr;
      Ls[r * LP + j] = (float)(accd[jj][rr] + (double)cj);
    }
  }
  __syncthreads();

  if (t < ROWS) {
    const int row = row0 + t;
    float L[32];
#pragma unroll
    for (int j = 0; j < 32; ++j) L[j] = Ls[t * LP + j];

    float nrv[16];
#pragma unroll
    for (int q = 0; q < 4; ++q) {
      float4 v = *(const float4*)&nr[(size_t)row * 16 + 4 * q];
      nrv[4 * q] = v.x; nrv[4 * q + 1] = v.y; nrv[4 * q + 2] = v.z; nrv[4 * q + 3] = v.w;
    }

    float lg[16];
#pragma unroll
    for (int p = 0; p < 16; ++p) {
      const float x = L[16 + p];
      const float sp = (x > 15.f) ? x : log1pf(expf(x));   // softplus
      lg[p] = L[p] + nrv[p] * sp;
    }

    float mx = lg[0];
#pragma unroll
    for (int p = 1; p < 16; ++p) mx = fmaxf(mx, lg[p]);
    float e[16]; float sum = 0.f;
#pragma unroll
    for (int p = 0; p < 16; ++p) { e[p] = expf(lg[p] - mx); sum += e[p]; }
    float w[16];
#pragma unroll
    for (int p = 0; p < 16; ++p) w[p] = e[p] / sum;

    // top-4, strict > scan => lowest index wins ties (jax.lax.top_k semantics)
    int idx[4]; float val[4]; unsigned used = 0;
#pragma unroll
    for (int kk = 0; kk < 4; ++kk) {
      float best = -1.f; int bi = 0;
#pragma unroll
      for (int p = 0; p < 16; ++p) {
        const bool ok = (((used >> p) & 1u) == 0u) && (w[p] > best);
        best = ok ? w[p] : best;
        bi = ok ? p : bi;
      }
      idx[kk] = bi; val[kk] = best; used |= (1u << bi);
    }

    float so[16];
#pragma unroll
    for (int p = 0; p < 16; ++p) {
      float v = 0.f;
#pragma unroll
      for (int kk = 0; kk < 4; ++kk) v = (idx[kk] == p) ? val[kk] : v;
      so[p] = v;
    }
#pragma unroll
    for (int q = 0; q < 4; ++q)
      *(float4*)&out[(size_t)row * 16 + 4 * q] =
          make_float4(so[4 * q], so[4 * q + 1], so[4 * q + 2], so[4 * q + 3]);

    float4 pv, iv;
    pv.x = (float)patches[idx[0]]; pv.y = (float)patches[idx[1]];
    pv.z = (float)patches[idx[2]]; pv.w = (float)patches[idx[3]];
    iv.x = (float)idx[0]; iv.y = (float)idx[1];
    iv.z = (float)idx[2]; iv.w = (float)idx[3];
    *(float4*)&out[(size_t)B_ROWS * 16 + (size_t)row * 4] = pv;
    *(float4*)&out[(size_t)B_ROWS * 20 + (size_t)row * 4] = iv;
  }
}

// ---------------- launcher ---------------------------------------------------
extern "C" void kernel_launch(void* const* d_in, const int* in_sizes, int n_in,
                              void* d_out, int out_size, void* d_ws, size_t ws_size,
                              hipStream_t stream) {
  const float* zn = (const float*)d_in[0];
  const float* zs = (const float*)d_in[1];
  const float* zt = (const float*)d_in[2];
  const float* nz = (const float*)d_in[3];
  const float* nr = (const float*)d_in[4];
  const int*   pc = (const int*)d_in[5];
  const float* Wp = (const float*)d_in[6];
  const float* bp = (const float*)d_in[7];
  const float* Wr = (const float*)d_in[8];
  const float* br = (const float*)d_in[9];
  const float* Wn = (const float*)d_in[10];
  const float* bn = (const float*)d_in[11];
  float* out = (float*)d_out;
  float* M = (float*)d_ws;            // 32*1024 floats
  float* c = M + 32 * 1024;           // 32 floats

  precompute_M<<<128, 256, 0, stream>>>(Wp, Wr, Wn, bp, br, bn, M, c);
  router_main<<<B_ROWS / ROWS, 256, 0, stream>>>(zn, zs, zt, nz, nr, pc, M, c, out);
}